// Round 1
// baseline (563.768 us; speedup 1.0000x reference)
//
#include <hip/hip_runtime.h>

#define B_DIM 256
#define K_DIM 256
#define H_DIM 1024
#define SEQ_DIM 128
#define L_DIM 3
#define NCH 8
#define BCH (B_DIM / NCH)   // 32 b's per chunk

// ---------------- kernel 1: scores[b,k] = dot(x[b,:], S[b,k,:]) ----------------
// one wave per (b,k); block = 4 waves
__global__ void k_scores(const float* __restrict__ ent, const float* __restrict__ S,
                         float* __restrict__ scores) {
    int tid  = threadIdx.x;
    int wave = tid >> 6, lane = tid & 63;
    int pi = blockIdx.x * 4 + wave;
    int b = pi >> 8, k = pi & 255;
    const float* srow = S   + ((size_t)(b * K_DIM + k)) * H_DIM;
    const float* xrow = ent + (size_t)b * SEQ_DIM * H_DIM;   // entity_encoding[b,0,:]
    float dot = 0.f;
#pragma unroll
    for (int r = 0; r < 4; ++r) {
        int idx = r * 256 + lane * 4;
        float4 s4 = *(const float4*)(srow + idx);
        float4 x4 = *(const float4*)(xrow + idx);
        dot += s4.x * x4.x + s4.y * x4.y + s4.z * x4.z + s4.w * x4.w;
    }
#pragma unroll
    for (int off = 32; off > 0; off >>= 1) dot += __shfl_down(dot, off, 64);
    if (lane == 0) scores[b * K_DIM + k] = dot;
}

// ---------------- kernel 2: softmax over b (axis=0) per k ----------------
// block per k (grid=256), thread per b (block=256); p stored transposed [k][b]
__global__ void k_softmax(const float* __restrict__ scores, float* __restrict__ p_t) {
    __shared__ float sm[B_DIM];
    int b = threadIdx.x, k = blockIdx.x;
    float s = scores[b * K_DIM + k];
    sm[b] = s; __syncthreads();
    for (int off = 128; off > 0; off >>= 1) {
        if (b < off) sm[b] = fmaxf(sm[b], sm[b + off]);
        __syncthreads();
    }
    float m = sm[0]; __syncthreads();
    float e = expf(s - m);
    sm[b] = e; __syncthreads();
    for (int off = 128; off > 0; off >>= 1) {
        if (b < off) sm[b] += sm[b + off];
        __syncthreads();
    }
    p_t[k * B_DIM + b] = e / sm[0];
}

// ---------------- kernel 3: partial u[k,h] over a b-chunk ----------------
// grid (K, NCH), block 256; thread t owns h = t*4..t*4+3
__global__ void k_weighted(const float* __restrict__ S, const float* __restrict__ p_t,
                           float* __restrict__ u_part) {
    int k = blockIdx.x, c = blockIdx.y, t = threadIdx.x;
    float4 acc = {0.f, 0.f, 0.f, 0.f};
    const float* pk = p_t + k * B_DIM;
    int b0 = c * BCH;
    for (int bb = 0; bb < BCH; ++bb) {
        int b = b0 + bb;
        float w = pk[b];
        float4 s4 = *(const float4*)(S + ((size_t)(b * K_DIM + k)) * H_DIM + t * 4);
        acc.x += w * s4.x; acc.y += w * s4.y; acc.z += w * s4.z; acc.w += w * s4.w;
    }
    *(float4*)(u_part + ((size_t)(c * K_DIM + k)) * H_DIM + t * 4) = acc;
}

// ---------------- kernel 3b: reduce the NCH partials ----------------
// grid 256, block 256, one float4 per thread
__global__ void k_reduce_u(const float* __restrict__ u_part, float* __restrict__ u) {
    int idx = blockIdx.x * 256 + threadIdx.x;     // float4 index, 0..65535
    float4 acc = {0.f, 0.f, 0.f, 0.f};
#pragma unroll
    for (int c = 0; c < NCH; ++c) {
        float4 v = *(const float4*)(u_part + (size_t)c * K_DIM * H_DIM + (size_t)idx * 4);
        acc.x += v.x; acc.y += v.y; acc.z += v.z; acc.w += v.w;
    }
    *(float4*)(u + (size_t)idx * 4) = acc;
}

// ---------------- kernel 4: act = prelu(x + U @ H_w^T) ----------------
// 64x64 tile, block 256 threads, 4x4 micro-tile per thread
__global__ void k_vgemm(const float* __restrict__ u, const float* __restrict__ Hw,
                        const float* __restrict__ ent, const float* __restrict__ alpha,
                        float* __restrict__ act) {
    __shared__ float Us[64][17];
    __shared__ float Hs[64][17];
    int tid = threadIdx.x;
    int tx = tid & 15, ty = tid >> 4;           // tx: h micro, ty: b micro
    int hx = blockIdx.x * 64, by = blockIdx.y * 64;
    float acc[4][4] = {};
    int li = tid * 4;
    int r = li >> 4, cc = li & 15;              // 4 threads per row, cc in {0,4,8,12}
    for (int kk0 = 0; kk0 < H_DIM; kk0 += 16) {
        float4 uv = *(const float4*)(u  + (size_t)(by + r) * H_DIM + kk0 + cc);
        float4 hv = *(const float4*)(Hw + (size_t)(hx + r) * H_DIM + kk0 + cc);
        Us[r][cc] = uv.x; Us[r][cc + 1] = uv.y; Us[r][cc + 2] = uv.z; Us[r][cc + 3] = uv.w;
        Hs[r][cc] = hv.x; Hs[r][cc + 1] = hv.y; Hs[r][cc + 2] = hv.z; Hs[r][cc + 3] = hv.w;
        __syncthreads();
#pragma unroll
        for (int kk = 0; kk < 16; ++kk) {
            float a[4], bv[4];
#pragma unroll
            for (int i = 0; i < 4; ++i) a[i]  = Us[ty * 4 + i][kk];
#pragma unroll
            for (int j = 0; j < 4; ++j) bv[j] = Hs[tx * 4 + j][kk];
#pragma unroll
            for (int i = 0; i < 4; ++i)
#pragma unroll
                for (int j = 0; j < 4; ++j) acc[i][j] += a[i] * bv[j];
        }
        __syncthreads();
    }
#pragma unroll
    for (int i = 0; i < 4; ++i) {
        int b = by + ty * 4 + i;
        const float* xrow = ent + (size_t)b * SEQ_DIM * H_DIM;
#pragma unroll
        for (int j = 0; j < 4; ++j) {
            int h = hx + tx * 4 + j;
            float v = xrow[h] + acc[i][j];
            float av = (v >= 0.f) ? v : alpha[h] * v;
            act[(size_t)b * H_DIM + h] = av;
        }
    }
}

// ---------------- kernel 5: out = act @ R_w^T ----------------
// block per b, 256 threads, 3 dots of length 1024
__global__ void k_out(const float* __restrict__ act, const float* __restrict__ Rw,
                      float* __restrict__ out) {
    __shared__ float sm[4 * L_DIM];
    int b = blockIdx.x, t = threadIdx.x;
    float4 a4 = *(const float4*)(act + (size_t)b * H_DIM + t * 4);
    float p[L_DIM];
#pragma unroll
    for (int l = 0; l < L_DIM; ++l) {
        float4 r4 = *(const float4*)(Rw + l * H_DIM + t * 4);
        p[l] = a4.x * r4.x + a4.y * r4.y + a4.z * r4.z + a4.w * r4.w;
    }
#pragma unroll
    for (int off = 32; off > 0; off >>= 1) {
#pragma unroll
        for (int l = 0; l < L_DIM; ++l) p[l] += __shfl_down(p[l], off, 64);
    }
    int lane = t & 63, wave = t >> 6;
    if (lane == 0) {
#pragma unroll
        for (int l = 0; l < L_DIM; ++l) sm[wave * L_DIM + l] = p[l];
    }
    __syncthreads();
    if (t < L_DIM) {
        float s = sm[t] + sm[L_DIM + t] + sm[2 * L_DIM + t] + sm[3 * L_DIM + t];
        out[b * L_DIM + t] = s;
    }
}

extern "C" void kernel_launch(void* const* d_in, const int* in_sizes, int n_in,
                              void* d_out, int out_size, void* d_ws, size_t ws_size,
                              hipStream_t stream) {
    const float* ent   = (const float*)d_in[0];   // (256,128,1024)
    const float* S     = (const float*)d_in[1];   // (256, 256*1024)
    const float* Hw    = (const float*)d_in[2];   // (1024,1024)
    const float* Rw    = (const float*)d_in[3];   // (3,1024)
    const float* alpha = (const float*)d_in[4];   // (1024,)
    float* out = (float*)d_out;                   // (256,3)

    // workspace layout (floats)
    float* ws      = (float*)d_ws;
    float* scores  = ws;                          //  65536
    float* p_t     = scores + 65536;              //  65536
    float* u_part  = p_t + 65536;                 //  NCH*256*1024 = 2097152
    float* u       = u_part + (size_t)NCH * K_DIM * H_DIM;  // 262144
    float* act     = u + (size_t)K_DIM * H_DIM;   // 262144
    // total ~10.5 MB

    k_scores  <<<(B_DIM * K_DIM) / 4, 256, 0, stream>>>(ent, S, scores);
    k_softmax <<<K_DIM, B_DIM, 0, stream>>>(scores, p_t);
    k_weighted<<<dim3(K_DIM, NCH), 256, 0, stream>>>(S, p_t, u_part);
    k_reduce_u<<<K_DIM, 256, 0, stream>>>(u_part, u);
    k_vgemm   <<<dim3(H_DIM / 64, B_DIM / 64), 256, 0, stream>>>(u, Hw, ent, alpha, act);
    k_out     <<<B_DIM, 256, 0, stream>>>(act, Rw, out);
}

// Round 2
// 441.611 us; speedup vs baseline: 1.2766x; 1.2766x over previous
//
#include <hip/hip_runtime.h>
#include <math.h>

#define B_DIM 256
#define K_DIM 256
#define H_DIM 1024
#define SEQ_DIM 128
#define L_DIM 3
#define NSPLIT 4
#define BS (B_DIM / NSPLIT)     // 64 b's per flash block
#define SK 4                    // split-K for the H x H gemm

// ---------------- kernel 1: flash-style online softmax-weighted sum ----------------
// grid (K, NSPLIT), block 256 (4 waves). Each block: k fixed, iterates 64 b's.
// Produces num[sp][k][h] = sum_b e^{s_b - m} * S[b,k,h], and (m, l) per (sp,k).
__global__ void k_flash(const float* __restrict__ ent, const float* __restrict__ S,
                        float* __restrict__ num, float* __restrict__ ml) {
    int k = blockIdx.x, sp = blockIdx.y, t = threadIdx.x;
    int lane = t & 63, wave = t >> 6;
    __shared__ float red[2][4];

    float4 acc = {0.f, 0.f, 0.f, 0.f};
    float m = -INFINITY, l = 0.f;
    int b0 = sp * BS;

    const float* Sp = S   + ((size_t)(b0 * K_DIM + k)) * H_DIM + t * 4;
    const float* Xp = ent + (size_t)b0 * SEQ_DIM * H_DIM + t * 4;

    float4 s4 = *(const float4*)Sp;
    float4 x4 = *(const float4*)Xp;

    for (int bb = 0; bb < BS; ++bb) {
        float4 s4n = {0.f, 0.f, 0.f, 0.f}, x4n = {0.f, 0.f, 0.f, 0.f};
        if (bb + 1 < BS) {
            // prefetch next row before the barrier: load latency overlaps the reduce
            s4n = *(const float4*)(Sp + (size_t)(bb + 1) * K_DIM * H_DIM);
            x4n = *(const float4*)(Xp + (size_t)(bb + 1) * SEQ_DIM * H_DIM);
        }
        float partial = s4.x * x4.x + s4.y * x4.y + s4.z * x4.z + s4.w * x4.w;
#pragma unroll
        for (int off = 32; off > 0; off >>= 1) partial += __shfl_down(partial, off, 64);
        if (lane == 0) red[bb & 1][wave] = partial;
        __syncthreads();
        float s = red[bb & 1][0] + red[bb & 1][1] + red[bb & 1][2] + red[bb & 1][3];

        float mn = fmaxf(m, s);
        float scale = expf(m - mn);     // m = -inf on first iter -> scale = 0
        float e = expf(s - mn);
        acc.x = acc.x * scale + e * s4.x;
        acc.y = acc.y * scale + e * s4.y;
        acc.z = acc.z * scale + e * s4.z;
        acc.w = acc.w * scale + e * s4.w;
        l = l * scale + e;
        m = mn;

        s4 = s4n; x4 = x4n;
    }
    *(float4*)(num + ((size_t)(sp * K_DIM + k)) * H_DIM + t * 4) = acc;
    if (t == 0) {
        ml[sp * K_DIM + k] = m;
        ml[NSPLIT * K_DIM + sp * K_DIM + k] = l;
    }
}

// ---------------- kernel 2: merge the NSPLIT online-softmax partials ----------------
// grid K, block 256. u[k,h] = sum_sp e^{m_sp - M} num_sp[h] / sum_sp e^{m_sp - M} l_sp
__global__ void k_combine(const float* __restrict__ num, const float* __restrict__ ml,
                          float* __restrict__ u) {
    int k = blockIdx.x, t = threadIdx.x;
    float M = -INFINITY;
#pragma unroll
    for (int sp = 0; sp < NSPLIT; ++sp) M = fmaxf(M, ml[sp * K_DIM + k]);
    float w[NSPLIT];
    float denom = 0.f;
#pragma unroll
    for (int sp = 0; sp < NSPLIT; ++sp) {
        w[sp] = expf(ml[sp * K_DIM + k] - M);
        denom += w[sp] * ml[NSPLIT * K_DIM + sp * K_DIM + k];
    }
    float inv = 1.f / denom;
    float4 a = {0.f, 0.f, 0.f, 0.f};
#pragma unroll
    for (int sp = 0; sp < NSPLIT; ++sp) {
        float4 n4 = *(const float4*)(num + ((size_t)(sp * K_DIM + k)) * H_DIM + t * 4);
        a.x += w[sp] * n4.x; a.y += w[sp] * n4.y; a.z += w[sp] * n4.z; a.w += w[sp] * n4.w;
    }
    a.x *= inv; a.y *= inv; a.z *= inv; a.w *= inv;
    *(float4*)(u + (size_t)k * H_DIM + t * 4) = a;
}

// ---------------- kernel 3: split-K vector GEMM, vpart[z][b][h] = U[b, ks] @ Hw[h, ks]^T ----
// 64x64 tile, block 256 threads, 4x4 micro-tile; grid (H/64, B/64, SK)
__global__ void k_vgemm(const float* __restrict__ u, const float* __restrict__ Hw,
                        float* __restrict__ vpart) {
    __shared__ float Us[64][17];
    __shared__ float Hs[64][17];
    int tid = threadIdx.x;
    int tx = tid & 15, ty = tid >> 4;
    int hx = blockIdx.x * 64, by = blockIdx.y * 64, z = blockIdx.z;
    float acc[4][4] = {};
    int li = tid * 4;
    int r = li >> 4, cc = li & 15;
    int k0 = z * (H_DIM / SK), k1 = k0 + (H_DIM / SK);
    for (int kk0 = k0; kk0 < k1; kk0 += 16) {
        float4 uv = *(const float4*)(u  + (size_t)(by + r) * H_DIM + kk0 + cc);
        float4 hv = *(const float4*)(Hw + (size_t)(hx + r) * H_DIM + kk0 + cc);
        Us[r][cc] = uv.x; Us[r][cc + 1] = uv.y; Us[r][cc + 2] = uv.z; Us[r][cc + 3] = uv.w;
        Hs[r][cc] = hv.x; Hs[r][cc + 1] = hv.y; Hs[r][cc + 2] = hv.z; Hs[r][cc + 3] = hv.w;
        __syncthreads();
#pragma unroll
        for (int kk = 0; kk < 16; ++kk) {
            float a[4], bv[4];
#pragma unroll
            for (int i = 0; i < 4; ++i) a[i]  = Us[ty * 4 + i][kk];
#pragma unroll
            for (int j = 0; j < 4; ++j) bv[j] = Hs[tx * 4 + j][kk];
#pragma unroll
            for (int i = 0; i < 4; ++i)
#pragma unroll
                for (int j = 0; j < 4; ++j) acc[i][j] += a[i] * bv[j];
        }
        __syncthreads();
    }
#pragma unroll
    for (int i = 0; i < 4; ++i) {
        int b = by + ty * 4 + i;
#pragma unroll
        for (int j = 0; j < 4; ++j) {
            int h = hx + tx * 4 + j;
            vpart[((size_t)z * B_DIM + b) * H_DIM + h] = acc[i][j];
        }
    }
}

// ---------------- kernel 4: fuse split-K reduce + x add + PReLU + R_w projection ----
// grid B, block 256. out[b,l] = sum_h prelu(x[b,h] + sum_z vpart[z][b][h]) * Rw[l,h]
__global__ void k_final(const float* __restrict__ vpart, const float* __restrict__ ent,
                        const float* __restrict__ alpha, const float* __restrict__ Rw,
                        float* __restrict__ out) {
    __shared__ float sm[4 * L_DIM];
    int b = blockIdx.x, t = threadIdx.x;
    int lane = t & 63, wave = t >> 6;
    float4 v = *(const float4*)(ent + (size_t)b * SEQ_DIM * H_DIM + t * 4);
#pragma unroll
    for (int z = 0; z < SK; ++z) {
        float4 p4 = *(const float4*)(vpart + ((size_t)z * B_DIM + b) * H_DIM + t * 4);
        v.x += p4.x; v.y += p4.y; v.z += p4.z; v.w += p4.w;
    }
    float4 al = *(const float4*)(alpha + t * 4);
    v.x = (v.x >= 0.f) ? v.x : al.x * v.x;
    v.y = (v.y >= 0.f) ? v.y : al.y * v.y;
    v.z = (v.z >= 0.f) ? v.z : al.z * v.z;
    v.w = (v.w >= 0.f) ? v.w : al.w * v.w;
    float p[L_DIM];
#pragma unroll
    for (int l = 0; l < L_DIM; ++l) {
        float4 r4 = *(const float4*)(Rw + l * H_DIM + t * 4);
        p[l] = v.x * r4.x + v.y * r4.y + v.z * r4.z + v.w * r4.w;
    }
#pragma unroll
    for (int off = 32; off > 0; off >>= 1) {
#pragma unroll
        for (int l = 0; l < L_DIM; ++l) p[l] += __shfl_down(p[l], off, 64);
    }
    if (lane == 0) {
#pragma unroll
        for (int l = 0; l < L_DIM; ++l) sm[wave * L_DIM + l] = p[l];
    }
    __syncthreads();
    if (t < L_DIM) {
        out[b * L_DIM + t] = sm[t] + sm[L_DIM + t] + sm[2 * L_DIM + t] + sm[3 * L_DIM + t];
    }
}

extern "C" void kernel_launch(void* const* d_in, const int* in_sizes, int n_in,
                              void* d_out, int out_size, void* d_ws, size_t ws_size,
                              hipStream_t stream) {
    const float* ent   = (const float*)d_in[0];   // (256,128,1024)
    const float* S     = (const float*)d_in[1];   // (256, 256*1024)
    const float* Hw    = (const float*)d_in[2];   // (1024,1024)
    const float* Rw    = (const float*)d_in[3];   // (3,1024)
    const float* alpha = (const float*)d_in[4];   // (1024,)
    float* out = (float*)d_out;                   // (256,3)

    // workspace layout (floats)
    float* ws    = (float*)d_ws;
    float* num   = ws;                                        // NSPLIT*K*H = 1M
    float* ml    = num + (size_t)NSPLIT * K_DIM * H_DIM;      // 2*NSPLIT*K = 2048
    float* u     = ml + 2 * NSPLIT * K_DIM;                   // K*H = 256K
    float* vpart = u + (size_t)K_DIM * H_DIM;                 // SK*B*H = 1M
    // total ~9.2 MB

    k_flash  <<<dim3(K_DIM, NSPLIT), 256, 0, stream>>>(ent, S, num, ml);
    k_combine<<<K_DIM, 256, 0, stream>>>(num, ml, u);
    k_vgemm  <<<dim3(H_DIM / 64, B_DIM / 64, SK), 256, 0, stream>>>(u, Hw, vpart);
    k_final  <<<B_DIM, 256, 0, stream>>>(vpart, ent, alpha, Rw, out);
}

// Round 3
// 440.440 us; speedup vs baseline: 1.2800x; 1.0027x over previous
//
#include <hip/hip_runtime.h>
#include <math.h>

#define B_DIM 256
#define K_DIM 256
#define H_DIM 1024
#define SEQ_DIM 128
#define L_DIM 3
#define NSPLIT 8
#define BS (B_DIM / NSPLIT)     // 32 b's per flash wave
#define SK 4                    // split-K for the H x H gemm

// ---------------- kernel 1: single-wave flash online softmax-weighted sum ----------------
// grid (K, NSPLIT), block 64 (ONE wave). Each wave: k fixed, iterates BS b's.
// No LDS, no __syncthreads: score reduce is 6 shfl_xor butterflies.
// Lane owns 16 strided floats: h = r*256 + lane*4 + {0..3}, r = 0..3.
__global__ __launch_bounds__(64) void k_flash(const float* __restrict__ ent,
                                              const float* __restrict__ S,
                                              float* __restrict__ num,
                                              float* __restrict__ ml) {
    int k = blockIdx.x, sp = blockIdx.y, lane = threadIdx.x;
    int b0 = sp * BS;

    const float* Sp = S   + ((size_t)(b0 * K_DIM + k)) * H_DIM;
    const float* Xp = ent + (size_t)b0 * SEQ_DIM * H_DIM;

    float4 acc[4] = {{0,0,0,0},{0,0,0,0},{0,0,0,0},{0,0,0,0}};
    float m = -INFINITY, l = 0.f;

    float4 sc[4], xc[4];
#pragma unroll
    for (int r = 0; r < 4; ++r) {
        int idx = r * 256 + lane * 4;
        sc[r] = *(const float4*)(Sp + idx);
        xc[r] = *(const float4*)(Xp + idx);
    }

    for (int bb = 0; bb < BS; ++bb) {
        float4 sn[4] = {{0,0,0,0},{0,0,0,0},{0,0,0,0},{0,0,0,0}};
        float4 xn[4] = {{0,0,0,0},{0,0,0,0},{0,0,0,0},{0,0,0,0}};
        if (bb + 1 < BS) {
            const float* Snp = Sp + (size_t)(bb + 1) * K_DIM * H_DIM;
            const float* Xnp = Xp + (size_t)(bb + 1) * SEQ_DIM * H_DIM;
#pragma unroll
            for (int r = 0; r < 4; ++r) {
                int idx = r * 256 + lane * 4;
                sn[r] = *(const float4*)(Snp + idx);
                xn[r] = *(const float4*)(Xnp + idx);
            }
        }
        float partial = 0.f;
#pragma unroll
        for (int r = 0; r < 4; ++r)
            partial += sc[r].x * xc[r].x + sc[r].y * xc[r].y
                     + sc[r].z * xc[r].z + sc[r].w * xc[r].w;
#pragma unroll
        for (int off = 1; off < 64; off <<= 1)
            partial += __shfl_xor(partial, off, 64);
        float s = partial;                       // full dot, all lanes

        float mn = fmaxf(m, s);
        float scale = expf(m - mn);              // first iter: expf(-inf)=0
        float e = expf(s - mn);
#pragma unroll
        for (int r = 0; r < 4; ++r) {
            acc[r].x = acc[r].x * scale + e * sc[r].x;
            acc[r].y = acc[r].y * scale + e * sc[r].y;
            acc[r].z = acc[r].z * scale + e * sc[r].z;
            acc[r].w = acc[r].w * scale + e * sc[r].w;
        }
        l = l * scale + e;
        m = mn;
#pragma unroll
        for (int r = 0; r < 4; ++r) { sc[r] = sn[r]; xc[r] = xn[r]; }
    }

    float* np = num + ((size_t)(sp * K_DIM + k)) * H_DIM;
#pragma unroll
    for (int r = 0; r < 4; ++r)
        *(float4*)(np + r * 256 + lane * 4) = acc[r];
    if (lane == 0) {
        ml[sp * K_DIM + k] = m;
        ml[NSPLIT * K_DIM + sp * K_DIM + k] = l;
    }
}

// ---------------- kernel 2: merge the NSPLIT online-softmax partials ----------------
__global__ void k_combine(const float* __restrict__ num, const float* __restrict__ ml,
                          float* __restrict__ u) {
    int k = blockIdx.x, t = threadIdx.x;
    float M = -INFINITY;
#pragma unroll
    for (int sp = 0; sp < NSPLIT; ++sp) M = fmaxf(M, ml[sp * K_DIM + k]);
    float w[NSPLIT];
    float denom = 0.f;
#pragma unroll
    for (int sp = 0; sp < NSPLIT; ++sp) {
        w[sp] = expf(ml[sp * K_DIM + k] - M);
        denom += w[sp] * ml[NSPLIT * K_DIM + sp * K_DIM + k];
    }
    float inv = 1.f / denom;
    float4 a = {0.f, 0.f, 0.f, 0.f};
#pragma unroll
    for (int sp = 0; sp < NSPLIT; ++sp) {
        float4 n4 = *(const float4*)(num + ((size_t)(sp * K_DIM + k)) * H_DIM + t * 4);
        a.x += w[sp] * n4.x; a.y += w[sp] * n4.y; a.z += w[sp] * n4.z; a.w += w[sp] * n4.w;
    }
    a.x *= inv; a.y *= inv; a.z *= inv; a.w *= inv;
    *(float4*)(u + (size_t)k * H_DIM + t * 4) = a;
}

// ---------------- kernel 3: split-K vector GEMM, vpart[z][b][h] = U[b, ks] @ Hw[h, ks]^T ----
__global__ void k_vgemm(const float* __restrict__ u, const float* __restrict__ Hw,
                        float* __restrict__ vpart) {
    __shared__ float Us[64][17];
    __shared__ float Hs[64][17];
    int tid = threadIdx.x;
    int tx = tid & 15, ty = tid >> 4;
    int hx = blockIdx.x * 64, by = blockIdx.y * 64, z = blockIdx.z;
    float acc[4][4] = {};
    int li = tid * 4;
    int r = li >> 4, cc = li & 15;
    int k0 = z * (H_DIM / SK), k1 = k0 + (H_DIM / SK);
    for (int kk0 = k0; kk0 < k1; kk0 += 16) {
        float4 uv = *(const float4*)(u  + (size_t)(by + r) * H_DIM + kk0 + cc);
        float4 hv = *(const float4*)(Hw + (size_t)(hx + r) * H_DIM + kk0 + cc);
        Us[r][cc] = uv.x; Us[r][cc + 1] = uv.y; Us[r][cc + 2] = uv.z; Us[r][cc + 3] = uv.w;
        Hs[r][cc] = hv.x; Hs[r][cc + 1] = hv.y; Hs[r][cc + 2] = hv.z; Hs[r][cc + 3] = hv.w;
        __syncthreads();
#pragma unroll
        for (int kk = 0; kk < 16; ++kk) {
            float a[4], bv[4];
#pragma unroll
            for (int i = 0; i < 4; ++i) a[i]  = Us[ty * 4 + i][kk];
#pragma unroll
            for (int j = 0; j < 4; ++j) bv[j] = Hs[tx * 4 + j][kk];
#pragma unroll
            for (int i = 0; i < 4; ++i)
#pragma unroll
                for (int j = 0; j < 4; ++j) acc[i][j] += a[i] * bv[j];
        }
        __syncthreads();
    }
#pragma unroll
    for (int i = 0; i < 4; ++i) {
        int b = by + ty * 4 + i;
#pragma unroll
        for (int j = 0; j < 4; ++j) {
            int h = hx + tx * 4 + j;
            vpart[((size_t)z * B_DIM + b) * H_DIM + h] = acc[i][j];
        }
    }
}

// ---------------- kernel 4: split-K reduce + x add + PReLU + R_w projection ----------------
__global__ void k_final(const float* __restrict__ vpart, const float* __restrict__ ent,
                        const float* __restrict__ alpha, const float* __restrict__ Rw,
                        float* __restrict__ out) {
    __shared__ float sm[4 * L_DIM];
    int b = blockIdx.x, t = threadIdx.x;
    int lane = t & 63, wave = t >> 6;
    float4 v = *(const float4*)(ent + (size_t)b * SEQ_DIM * H_DIM + t * 4);
#pragma unroll
    for (int z = 0; z < SK; ++z) {
        float4 p4 = *(const float4*)(vpart + ((size_t)z * B_DIM + b) * H_DIM + t * 4);
        v.x += p4.x; v.y += p4.y; v.z += p4.z; v.w += p4.w;
    }
    float4 al = *(const float4*)(alpha + t * 4);
    v.x = (v.x >= 0.f) ? v.x : al.x * v.x;
    v.y = (v.y >= 0.f) ? v.y : al.y * v.y;
    v.z = (v.z >= 0.f) ? v.z : al.z * v.z;
    v.w = (v.w >= 0.f) ? v.w : al.w * v.w;
    float p[L_DIM];
#pragma unroll
    for (int l = 0; l < L_DIM; ++l) {
        float4 r4 = *(const float4*)(Rw + l * H_DIM + t * 4);
        p[l] = v.x * r4.x + v.y * r4.y + v.z * r4.z + v.w * r4.w;
    }
#pragma unroll
    for (int off = 32; off > 0; off >>= 1) {
#pragma unroll
        for (int l = 0; l < L_DIM; ++l) p[l] += __shfl_down(p[l], off, 64);
    }
    if (lane == 0) {
#pragma unroll
        for (int l = 0; l < L_DIM; ++l) sm[wave * L_DIM + l] = p[l];
    }
    __syncthreads();
    if (t < L_DIM) {
        out[b * L_DIM + t] = sm[t] + sm[L_DIM + t] + sm[2 * L_DIM + t] + sm[3 * L_DIM + t];
    }
}

extern "C" void kernel_launch(void* const* d_in, const int* in_sizes, int n_in,
                              void* d_out, int out_size, void* d_ws, size_t ws_size,
                              hipStream_t stream) {
    const float* ent   = (const float*)d_in[0];   // (256,128,1024)
    const float* S     = (const float*)d_in[1];   // (256, 256*1024)
    const float* Hw    = (const float*)d_in[2];   // (1024,1024)
    const float* Rw    = (const float*)d_in[3];   // (3,1024)
    const float* alpha = (const float*)d_in[4];   // (1024,)
    float* out = (float*)d_out;                   // (256,3)

    float* ws    = (float*)d_ws;
    float* num   = ws;                                        // NSPLIT*K*H = 2M floats
    float* ml    = num + (size_t)NSPLIT * K_DIM * H_DIM;      // 2*NSPLIT*K
    float* u     = ml + 2 * NSPLIT * K_DIM;                   // K*H
    float* vpart = u + (size_t)K_DIM * H_DIM;                 // SK*B*H
    // total ~13.3 MB

    k_flash  <<<dim3(K_DIM, NSPLIT), 64, 0, stream>>>(ent, S, num, ml);
    k_combine<<<K_DIM, 256, 0, stream>>>(num, ml, u);
    k_vgemm  <<<dim3(H_DIM / 64, B_DIM / 64, SK), 256, 0, stream>>>(u, Hw, vpart);
    k_final  <<<B_DIM, 256, 0, stream>>>(vpart, ent, alpha, Rw, out);
}